// Round 10
// baseline (487.940 us; speedup 1.0000x reference)
//
#include <hip/hip_runtime.h>
#include <hip/hip_bf16.h>
#include <type_traits>

#define LQ    900
#define BSZ   8
#define ROWS  (LQ*BSZ)        // 7200
#define CDIM  256
#define QKS   512             // merged q|k row stride
#define OAS   480             // merged off|aw row stride
#define NH    8
#define DH    32
#define LVTOT 21824
#define VROWS (LVTOT*BSZ)     // 174592
#define DFF   2048

typedef unsigned short u16;
typedef short short8 __attribute__((ext_vector_type(8)));
typedef float f32x4 __attribute__((ext_vector_type(4)));

__device__ __forceinline__ u16 f2bf(float f) {
    __hip_bfloat16 h = __float2bfloat16(f);
    return *reinterpret_cast<u16*>(&h);
}
#define ATTN_SCALE 0.1767766952966369f

// ---------------- unified prep: 10 weight transposes (+scale) + bias concat ----------------
struct PrepArgs {
    const float* Wq; const float* Wk; const float* Wv; const float* Wo;
    const float* Wval; const float* Wout; const float* Woff; const float* Watt;
    const float* W1; const float* W2;
    u16* WqkT; u16* WvT; u16* WoT; u16* WvalT; u16* WoutT; u16* WoaT; u16* W1T; u16* W2T;
    const float* bq; const float* bk; const float* boff; const float* batt;
    float* bqk; float* boa;
};
__global__ __launch_bounds__(256) void prep_kernel(PrepArgs a) {
    __shared__ float t[32][33];
    const int id = blockIdx.x;
    if (id == 1528) {   // bias concat (scale folded into bq)
        const int tx = threadIdx.x;
        if (tx < 256) { a.bqk[tx] = a.bq[tx] * ATTN_SCALE; a.bqk[256 + tx] = a.bk[tx]; }
        for (int i = tx; i < 320; i += 256) a.boa[i] = a.boff[i];
        if (tx < 160) a.boa[320 + tx] = a.batt[tx];
        return;
    }
    const float* W; u16* Wt; int K = 256, N = 256, nx = 8; float scale = 1.f; int r;
    if      (id < 64)   { W = a.Wq;   Wt = a.WqkT;           scale = ATTN_SCALE; r = id; }
    else if (id < 128)  { W = a.Wk;   Wt = a.WqkT + 256*256; r = id - 64; }
    else if (id < 192)  { W = a.Wv;   Wt = a.WvT;            r = id - 128; }
    else if (id < 256)  { W = a.Wo;   Wt = a.WoT;            r = id - 192; }
    else if (id < 320)  { W = a.Wval; Wt = a.WvalT;          r = id - 256; }
    else if (id < 384)  { W = a.Wout; Wt = a.WoutT;          r = id - 320; }
    else if (id < 464)  { W = a.Woff; Wt = a.WoaT;           N = 320; nx = 10; r = id - 384; }
    else if (id < 504)  { W = a.Watt; Wt = a.WoaT + 320*256; N = 160; nx = 5;  r = id - 464; }
    else if (id < 1016) { W = a.W1;   Wt = a.W1T;            N = 2048; nx = 64; r = id - 504; }
    else                { W = a.W2;   Wt = a.W2T;            K = 2048; N = 256; nx = 8; r = id - 1016; }
    const int n0 = (r % nx) * 32, k0 = (r / nx) * 32;
    const int tx = threadIdx.x & 31, ty = threadIdx.x >> 5;
    #pragma unroll
    for (int rr = ty; rr < 32; rr += 8)
        t[rr][tx] = W[(size_t)(k0 + rr) * N + n0 + tx];
    __syncthreads();
    #pragma unroll
    for (int rr = ty; rr < 32; rr += 8)
        Wt[(size_t)(n0 + rr) * K + k0 + tx] = f2bf(t[tx][rr] * scale);
}

// ---------------- barrier-free direct-fragment MFMA GEMM body ----------------
// 128x128 tile, 4 waves (2x2). Each lane loads its A/B fragments straight from
// global memory (A: f32->bf16 in-reg, or bf16 raw; B: 16B bf16). No LDS, no
// __syncthreads in the K-loop -> loads for step t+1 stay in flight under step
// t's MFMAs (compiler counted-vmcnt). LDS (dynamic) only for bf16-out epilogue.
__device__ __forceinline__ short8 cvt8(float4 lo, float4 hi) {
    u16 t[8] = { f2bf(lo.x), f2bf(lo.y), f2bf(lo.z), f2bf(lo.w),
                 f2bf(hi.x), f2bf(hi.y), f2bf(hi.z), f2bf(hi.w) };
    return *reinterpret_cast<short8*>(t);
}

template<typename AT, int RELU, int ADD, typename OutT>
__device__ __forceinline__ void gemm_body(const AT* __restrict__ A, const float* __restrict__ A2,
                                          const u16* __restrict__ Wt, const float* __restrict__ bias,
                                          OutT* __restrict__ C, int M, int N, int K,
                                          int m0, int n0, int tid) {
    extern __shared__ u16 Sep[];
    const int lane = tid & 63;
    const int wr = (tid >> 7) & 1, wc = (tid >> 6) & 1;
    const int lr = lane & 15, lg = lane >> 4;
    int trow[4], ncol[4];
    #pragma unroll
    for (int i = 0; i < 4; ++i) {
        int r = m0 + wr*64 + i*16 + lr;
        trow[i] = (r < M) ? r : (M - 1);          // clamp; junk rows masked at store
        ncol[i] = n0 + wc*64 + i*16 + lr;          // weight rows padded -> safe
    }
    f32x4 acc[4][4] = {};
    const int ns = K >> 5;

    if constexpr (std::is_same<AT, float>::value) {
        float4 a0[4][2], a1[4][2], p0[4][2], p1[4][2];
        short8 b0[4], b1[4];
        auto issue = [&](float4 (&aa)[4][2], float4 (&pp)[4][2], short8 (&bb)[4], int k0) {
            #pragma unroll
            for (int i = 0; i < 4; ++i) {
                const float* p = &A[(size_t)trow[i]*K + k0 + lg*8];
                aa[i][0] = *reinterpret_cast<const float4*>(p);
                aa[i][1] = *reinterpret_cast<const float4*>(p + 4);
                if constexpr (ADD) {
                    const float* q = &A2[(size_t)trow[i]*K + k0 + lg*8];
                    pp[i][0] = *reinterpret_cast<const float4*>(q);
                    pp[i][1] = *reinterpret_cast<const float4*>(q + 4);
                }
            }
            #pragma unroll
            for (int j = 0; j < 4; ++j)
                bb[j] = *reinterpret_cast<const short8*>(&Wt[(size_t)ncol[j]*K + k0 + lg*8]);
        };
        auto comp = [&](float4 (&aa)[4][2], float4 (&pp)[4][2], short8 (&bb)[4]) {
            short8 af[4];
            #pragma unroll
            for (int i = 0; i < 4; ++i) {
                float4 lo = aa[i][0], hi = aa[i][1];
                if constexpr (ADD) {
                    lo.x += pp[i][0].x; lo.y += pp[i][0].y; lo.z += pp[i][0].z; lo.w += pp[i][0].w;
                    hi.x += pp[i][1].x; hi.y += pp[i][1].y; hi.z += pp[i][1].z; hi.w += pp[i][1].w;
                }
                af[i] = cvt8(lo, hi);
            }
            #pragma unroll
            for (int i = 0; i < 4; ++i)
                #pragma unroll
                for (int j = 0; j < 4; ++j)
                    acc[i][j] = __builtin_amdgcn_mfma_f32_16x16x32_bf16(af[i], bb[j], acc[i][j], 0, 0, 0);
        };
        issue(a0, p0, b0, 0);
        for (int t = 0; t < ns; t += 2) {          // ns always even (K=256/2048)
            issue(a1, p1, b1, (t + 1) << 5);
            comp(a0, p0, b0);
            if (t + 2 < ns) issue(a0, p0, b0, (t + 2) << 5);
            comp(a1, p1, b1);
        }
    } else {
        short8 a0[4], a1[4], b0[4], b1[4];
        auto issue = [&](short8 (&aa)[4], short8 (&bb)[4], int k0) {
            #pragma unroll
            for (int i = 0; i < 4; ++i)
                aa[i] = *reinterpret_cast<const short8*>(&((const u16*)A)[(size_t)trow[i]*K + k0 + lg*8]);
            #pragma unroll
            for (int j = 0; j < 4; ++j)
                bb[j] = *reinterpret_cast<const short8*>(&Wt[(size_t)ncol[j]*K + k0 + lg*8]);
        };
        auto comp = [&](short8 (&aa)[4], short8 (&bb)[4]) {
            #pragma unroll
            for (int i = 0; i < 4; ++i)
                #pragma unroll
                for (int j = 0; j < 4; ++j)
                    acc[i][j] = __builtin_amdgcn_mfma_f32_16x16x32_bf16(aa[i], bb[j], acc[i][j], 0, 0, 0);
        };
        issue(a0, b0, 0);
        for (int t = 0; t < ns; t += 2) {
            issue(a1, b1, (t + 1) << 5);
            comp(a0, b0);
            if (t + 2 < ns) issue(a0, b0, (t + 2) << 5);
            comp(a1, b1);
        }
    }

    if constexpr (std::is_same<OutT, float>::value) {
        #pragma unroll
        for (int j = 0; j < 4; ++j) {
            const int col = n0 + wc*64 + j*16 + lr;
            if (col >= N) continue;
            const float bcol = bias[col];
            #pragma unroll
            for (int i = 0; i < 4; ++i) {
                #pragma unroll
                for (int r = 0; r < 4; ++r) {
                    const int row = m0 + wr*64 + i*16 + lg*4 + r;
                    if (row >= M) continue;
                    float v = acc[i][j][r] + bcol;
                    if (RELU) v = fmaxf(v, 0.f);
                    C[(size_t)row * N + col] = v;
                }
            }
        }
    } else {
        // LDS-staged coalesced bf16 epilogue (N multiple of 128 on this path)
        __syncthreads();
        #pragma unroll
        for (int j = 0; j < 4; ++j) {
            const int col = wc*64 + j*16 + lr;
            const float bcol = bias[n0 + col];
            #pragma unroll
            for (int i = 0; i < 4; ++i)
                #pragma unroll
                for (int r = 0; r < 4; ++r) {
                    float v = acc[i][j][r] + bcol;
                    if (RELU) v = fmaxf(v, 0.f);
                    Sep[(wr*64 + i*16 + lg*4 + r)*128 + col] = f2bf(v);
                }
        }
        __syncthreads();
        #pragma unroll
        for (int it = 0; it < 8; ++it) {
            const int idx = it*256 + tid;
            const int row = idx >> 4, cc = idx & 15;
            if (m0 + row < M)
                *reinterpret_cast<uint4*>(&C[(size_t)(m0 + row) * N + n0 + cc*8]) =
                    *reinterpret_cast<const uint4*>(&Sep[row*128 + cc*8]);
        }
    }
}

template<typename AT, int RELU, int ADD, typename OutT>
__global__ __launch_bounds__(256) void gemm_direct(const AT* __restrict__ A, const float* __restrict__ A2,
                                                   const u16* __restrict__ Wt, const float* __restrict__ bias,
                                                   OutT* __restrict__ C, int M, int N, int K) {
    gemm_body<AT, RELU, ADD, OutT>(A, A2, Wt, bias, C, M, N, K,
                                   blockIdx.y * 128, blockIdx.x * 128, threadIdx.x);
}

// merged value | qk | v dispatch (all K=256, bf16 out)
__global__ __launch_bounds__(256) void mgemm3_kernel(
        const float* __restrict__ Aval, const u16* __restrict__ WvalT, const float* __restrict__ bval, u16* __restrict__ Cval,
        const float* __restrict__ Aqk,  const float* __restrict__ Aqk2, const u16* __restrict__ WqkT,
        const float* __restrict__ bqk,  u16* __restrict__ Cqk,
        const float* __restrict__ Av,   const u16* __restrict__ WvT,   const float* __restrict__ bv, u16* __restrict__ Cv) {
    int id = blockIdx.x;
    if (id < 2728) {
        gemm_body<float,0,0,u16>(Aval, nullptr, WvalT, bval, Cval, VROWS, 256, 256,
                                 (id >> 1) * 128, (id & 1) * 128, threadIdx.x);
    } else if (id < 2956) {
        id -= 2728;
        gemm_body<float,0,1,u16>(Aqk, Aqk2, WqkT, bqk, Cqk, ROWS, 512, 256,
                                 (id >> 2) * 128, (id & 3) * 128, threadIdx.x);
    } else {
        id -= 2956;
        gemm_body<float,0,0,u16>(Av, nullptr, WvT, bv, Cv, ROWS, 256, 256,
                                 (id >> 1) * 128, (id & 1) * 128, threadIdx.x);
    }
}

// ---------------- MFMA flash self-attention (bf16 q/k/v in) ----------------
__global__ __launch_bounds__(256) void attn_mfma_kernel(const u16* __restrict__ qkb,
                                                        const u16* __restrict__ vb,
                                                        float* __restrict__ out) {
    __shared__ __align__(16) u16 Ks[64*32];
    __shared__ __align__(16) u16 Vt[32*64];
    const int bx = blockIdx.x;
    const int qt = bx & 7, h = (bx >> 3) & 7, b = bx >> 6;
    const int tid = threadIdx.x;
    const int w = tid >> 6, lane = tid & 63;
    const int lr = lane & 15, lg = lane >> 4;
    const int m0 = qt*128 + w*32;

    short8 qf[2];
    #pragma unroll
    for (int j = 0; j < 2; ++j) {
        int lq = m0 + j*16 + lr; if (lq > LQ-1) lq = LQ-1;
        qf[j] = *reinterpret_cast<const short8*>(&qkb[((size_t)lq*BSZ + b)*QKS + h*DH + lg*8]);
    }

    f32x4 o00 = {}, o01 = {}, o10 = {}, o11 = {};
    float m[2] = {-1e30f, -1e30f}, l[2] = {0.f, 0.f};
    const f32x4 zero = {};

    for (int kt = 0; kt < 15; ++kt) {
        __syncthreads();
        {
            const int key = tid >> 2, c = tid & 3;
            int kg = kt*64 + key; if (kg > LQ-1) kg = LQ-1;
            *reinterpret_cast<short8*>(&Ks[key*32 + ((c ^ ((key>>1)&3)) * 8)]) =
                *reinterpret_cast<const short8*>(&qkb[((size_t)kg*BSZ + b)*QKS + 256 + h*DH + c*8]);
            short8 vv = *reinterpret_cast<const short8*>(&vb[((size_t)kg*BSZ + b)*CDIM + h*DH + c*8]);
            const u16* pv = reinterpret_cast<const u16*>(&vv);
            #pragma unroll
            for (int e = 0; e < 8; ++e) {
                const int dh = c*8 + e;
                Vt[dh*64 + (((key>>3) ^ (dh&7)) * 8) + (key&7)] = pv[e];
            }
        }
        __syncthreads();

        f32x4 s[4][2];
        #pragma unroll
        for (int i = 0; i < 4; ++i) {
            const int key = i*16 + lr;
            short8 kf = *reinterpret_cast<const short8*>(&Ks[key*32 + ((lg ^ ((key>>1)&3)) * 8)]);
            s[i][0] = __builtin_amdgcn_mfma_f32_16x16x32_bf16(kf, qf[0], zero, 0, 0, 0);
            s[i][1] = __builtin_amdgcn_mfma_f32_16x16x32_bf16(kf, qf[1], zero, 0, 0, 0);
        }
        const int lim = LQ - kt*64 - lg*4;
        #pragma unroll
        for (int i = 0; i < 4; ++i)
            #pragma unroll
            for (int r = 0; r < 4; ++r)
                if (i*16 + r >= lim) { s[i][0][r] = -1e30f; s[i][1][r] = -1e30f; }

        #pragma unroll
        for (int j = 0; j < 2; ++j) {
            float mx = -1e30f;
            #pragma unroll
            for (int i = 0; i < 4; ++i)
                #pragma unroll
                for (int r = 0; r < 4; ++r) mx = fmaxf(mx, s[i][j][r]);
            mx = fmaxf(mx, __shfl_xor(mx, 16));
            mx = fmaxf(mx, __shfl_xor(mx, 32));
            const float mn = fmaxf(m[j], mx);
            const float corr = __expf(m[j] - mn);
            float sum = 0.f;
            #pragma unroll
            for (int i = 0; i < 4; ++i)
                #pragma unroll
                for (int r = 0; r < 4; ++r) {
                    float p = __expf(s[i][j][r] - mn);
                    s[i][j][r] = p;
                    sum += p;
                }
            sum += __shfl_xor(sum, 16);
            sum += __shfl_xor(sum, 32);
            l[j] = l[j]*corr + sum;
            m[j] = mn;
            if (j == 0) { o00 *= corr; o10 *= corr; }
            else        { o01 *= corr; o11 *= corr; }
        }

        short8 pb[2][2];
        #pragma unroll
        for (int kh = 0; kh < 2; ++kh)
            #pragma unroll
            for (int j = 0; j < 2; ++j) {
                u16 t[8];
                #pragma unroll
                for (int e = 0; e < 4; ++e) {
                    t[e]   = f2bf(s[2*kh][j][e]);
                    t[e+4] = f2bf(s[2*kh+1][j][e]);
                }
                pb[kh][j] = *reinterpret_cast<short8*>(t);
            }

        #pragma unroll
        for (int ip = 0; ip < 2; ++ip) {
            const int dh = ip*16 + lr;
            #pragma unroll
            for (int kh = 0; kh < 2; ++kh) {
                u16 t[8];
                const int c0 = (kh*4 + (lg>>1)) ^ (dh&7);
                const int c1 = (kh*4 + 2 + (lg>>1)) ^ (dh&7);
                *reinterpret_cast<uint2*>(&t[0]) =
                    *reinterpret_cast<const uint2*>(&Vt[dh*64 + c0*8 + (lg&1)*4]);
                *reinterpret_cast<uint2*>(&t[4]) =
                    *reinterpret_cast<const uint2*>(&Vt[dh*64 + c1*8 + (lg&1)*4]);
                short8 vf = *reinterpret_cast<short8*>(t);
                if (ip == 0) {
                    o00 = __builtin_amdgcn_mfma_f32_16x16x32_bf16(vf, pb[kh][0], o00, 0, 0, 0);
                    o01 = __builtin_amdgcn_mfma_f32_16x16x32_bf16(vf, pb[kh][1], o01, 0, 0, 0);
                } else {
                    o10 = __builtin_amdgcn_mfma_f32_16x16x32_bf16(vf, pb[kh][0], o10, 0, 0, 0);
                    o11 = __builtin_amdgcn_mfma_f32_16x16x32_bf16(vf, pb[kh][1], o11, 0, 0, 0);
                }
            }
        }
    }

    #pragma unroll
    for (int j = 0; j < 2; ++j) {
        const int lq = m0 + j*16 + lr;
        if (lq >= LQ) continue;
        const float inv = 1.f / l[j];
        float* op = &out[((size_t)lq*BSZ + b)*CDIM + h*DH];
        #pragma unroll
        for (int r = 0; r < 4; ++r) {
            const f32x4& a0 = (j == 0) ? o00 : o01;
            const f32x4& a1 = (j == 0) ? o10 : o11;
            op[lg*4 + r]      = a0[r] * inv;
            op[16 + lg*4 + r] = a1[r] * inv;
        }
    }
}

// ---------------- fused residual + LayerNorm ----------------
__global__ __launch_bounds__(256) void ln_res_kernel(const float* __restrict__ xin,
                                                     const float* __restrict__ res,
                                                     const float* __restrict__ g,
                                                     const float* __restrict__ beta,
                                                     float* __restrict__ out) {
    const int row  = blockIdx.x * 4 + (threadIdx.x >> 6);
    const int lane = threadIdx.x & 63;
    const size_t base = (size_t)row * CDIM + lane * 4;
    float4 a = *reinterpret_cast<const float4*>(&xin[base]);
    float4 r = *reinterpret_cast<const float4*>(&res[base]);
    float x0 = a.x+r.x, x1 = a.y+r.y, x2 = a.z+r.z, x3 = a.w+r.w;
    float s = x0+x1+x2+x3;
    #pragma unroll
    for (int o = 1; o < 64; o <<= 1) s += __shfl_xor(s, o);
    float mean = s * (1.f/256.f);
    float d0 = x0-mean, d1 = x1-mean, d2 = x2-mean, d3 = x3-mean;
    float sq = d0*d0 + d1*d1 + d2*d2 + d3*d3;
    #pragma unroll
    for (int o = 1; o < 64; o <<= 1) sq += __shfl_xor(sq, o);
    float rs = rsqrtf(sq * (1.f/256.f) + 1e-5f);
    float4 gg = *reinterpret_cast<const float4*>(&g[lane*4]);
    float4 bb = *reinterpret_cast<const float4*>(&beta[lane*4]);
    float4 o4 = make_float4(d0*rs*gg.x+bb.x, d1*rs*gg.y+bb.y, d2*rs*gg.z+bb.z, d3*rs*gg.w+bb.w);
    *reinterpret_cast<float4*>(&out[base]) = o4;
}

// ---------------- softmax over 20 (in merged oab buffer, offset 320) ----------------
__global__ __launch_bounds__(256) void softmax20_kernel(float* __restrict__ oab) {
    int item = blockIdx.x * 256 + threadIdx.x;
    if (item >= ROWS * NH) return;
    int row = item >> 3, h = item & 7;
    float* p = &oab[(size_t)row*OAS + 320 + h*20];
    float mx = -1e30f;
    float e[20];
    #pragma unroll
    for (int j = 0; j < 20; ++j) mx = fmaxf(mx, p[j]);
    float sum = 0.f;
    #pragma unroll
    for (int j = 0; j < 20; ++j) { e[j] = __expf(p[j] - mx); sum += e[j]; }
    float inv = 1.f / sum;
    #pragma unroll
    for (int j = 0; j < 20; ++j) p[j] = e[j] * inv;
}

// ---------------- ms-deformable sampling ----------------
__global__ __launch_bounds__(256) void msdeform_kernel(const u16* __restrict__ value,
                                                       const float* __restrict__ oab,
                                                       const float* __restrict__ refp,
                                                       float* __restrict__ samp) {
    const int gid = blockIdx.x * 32 + (threadIdx.x >> 3);  // row*8 + h
    const int ch  = (threadIdx.x & 7) * 4;
    const int h   = gid & 7;
    const int row = gid >> 3;
    const int b   = row & 7;
    const int WL[5] = {128, 64, 32, 16, 8};
    const int SL[5] = {0, 16384, 20480, 21504, 21760};
    const u16* vbase = value + h*DH + ch;
    float a0 = 0.f, a1 = 0.f, a2 = 0.f, a3 = 0.f;
    #pragma unroll
    for (int l = 0; l < 5; ++l) {
        const float2 r2 = *reinterpret_cast<const float2*>(&refp[((size_t)row*5 + l)*2]);
        const int W = WL[l];
        const float Wf = (float)W;
        #pragma unroll
        for (int p = 0; p < 4; ++p) {
            const float2 o2 = *reinterpret_cast<const float2*>(&oab[(size_t)row*OAS + ((h*5 + l)*4 + p)*2]);
            const float aw = oab[(size_t)row*OAS + 320 + h*20 + l*4 + p];
            const float x = (r2.x + o2.x / Wf) * Wf - 0.5f;
            const float y = (r2.y + o2.y / Wf) * Wf - 0.5f;
            const float x0f = floorf(x), y0f = floorf(y);
            const float fx = x - x0f, fy = y - y0f;
            const int x0 = (int)x0f, y0 = (int)y0f;
            float wx0 = (1.f - fx) * aw, wx1 = fx * aw;
            float fy0 = 1.f - fy, fy1 = fy;
            if (x0 < 0 || x0 >= W)       wx0 = 0.f;
            if (x0+1 < 0 || x0+1 >= W)   wx1 = 0.f;
            if (y0 < 0 || y0 >= W)       fy0 = 0.f;
            if (y0+1 < 0 || y0+1 >= W)   fy1 = 0.f;
            const float w00 = wx0*fy0, w10 = wx1*fy0, w01 = wx0*fy1, w11 = wx1*fy1;
            const int xc0 = min(max(x0, 0), W-1),   xc1 = min(max(x0+1, 0), W-1);
            const int yc0 = min(max(y0, 0), W-1),   yc1 = min(max(y0+1, 0), W-1);
            const int r0 = SL[l] + yc0*W, r1 = SL[l] + yc1*W;
            const int o00i = ((r0 + xc0)*BSZ + b) * CDIM;
            const int o10i = ((r0 + xc1)*BSZ + b) * CDIM;
            const int o01i = ((r1 + xc0)*BSZ + b) * CDIM;
            const int o11i = ((r1 + xc1)*BSZ + b) * CDIM;
            const uint2 u00 = *reinterpret_cast<const uint2*>(vbase + o00i);
            const uint2 u10 = *reinterpret_cast<const uint2*>(vbase + o10i);
            const uint2 u01 = *reinterpret_cast<const uint2*>(vbase + o01i);
            const uint2 u11 = *reinterpret_cast<const uint2*>(vbase + o11i);
            a0 += w00 * __uint_as_float(u00.x << 16) + w10 * __uint_as_float(u10.x << 16)
                + w01 * __uint_as_float(u01.x << 16) + w11 * __uint_as_float(u11.x << 16);
            a1 += w00 * __uint_as_float(u00.x & 0xffff0000u) + w10 * __uint_as_float(u10.x & 0xffff0000u)
                + w01 * __uint_as_float(u01.x & 0xffff0000u) + w11 * __uint_as_float(u11.x & 0xffff0000u);
            a2 += w00 * __uint_as_float(u00.y << 16) + w10 * __uint_as_float(u10.y << 16)
                + w01 * __uint_as_float(u01.y << 16) + w11 * __uint_as_float(u11.y << 16);
            a3 += w00 * __uint_as_float(u00.y & 0xffff0000u) + w10 * __uint_as_float(u10.y & 0xffff0000u)
                + w01 * __uint_as_float(u01.y & 0xffff0000u) + w11 * __uint_as_float(u11.y & 0xffff0000u);
        }
    }
    float4 o4 = make_float4(a0, a1, a2, a3);
    *reinterpret_cast<float4*>(&samp[(size_t)row*CDIM + h*DH + ch]) = o4;
}

// ---------------- launch ----------------
extern "C" void kernel_launch(void* const* d_in, const int* in_sizes, int n_in,
                              void* d_out, int out_size, void* d_ws, size_t ws_size,
                              hipStream_t stream) {
    (void)in_sizes; (void)n_in; (void)out_size; (void)ws_size;
    const float* tgt    = (const float*)d_in[0];
    const float* qpos   = (const float*)d_in[1];
    const float* refpts = (const float*)d_in[2];
    const float* memory = (const float*)d_in[3];
    const float* Wq  = (const float*)d_in[6];
    const float* Wk  = (const float*)d_in[7];
    const float* Wv  = (const float*)d_in[8];
    const float* Wo  = (const float*)d_in[9];
    const float* Woff= (const float*)d_in[10];
    const float* Watt= (const float*)d_in[11];
    const float* Wval= (const float*)d_in[12];
    const float* Wout= (const float*)d_in[13];
    const float* W1  = (const float*)d_in[14];
    const float* W2  = (const float*)d_in[15];
    const float* bq  = (const float*)d_in[16];
    const float* bk  = (const float*)d_in[17];
    const float* bv  = (const float*)d_in[18];
    const float* bo  = (const float*)d_in[19];
    const float* boff= (const float*)d_in[20];
    const float* batt= (const float*)d_in[21];
    const float* bval= (const float*)d_in[22];
    const float* bout= (const float*)d_in[23];
    const float* b1  = (const float*)d_in[24];
    const float* b2  = (const float*)d_in[25];
    const float* ln1g= (const float*)d_in[26];
    const float* ln1b= (const float*)d_in[27];
    const float* ln2g= (const float*)d_in[28];
    const float* ln2b= (const float*)d_in[29];
    const float* ln3g= (const float*)d_in[30];
    const float* ln3b= (const float*)d_in[31];
    float* out = (float*)d_out;

    char* ws = (char*)d_ws;
    const size_t RB = (size_t)ROWS * CDIM * 4;     // 7.37 MB
    float* tgt2  = (float*)(ws + 0*RB);
    float* tgt3  = (float*)(ws + 1*RB);
    float* qk    = (float*)(ws + 2*RB);            // sa-o / ca-o
    float* vbuf  = (float*)(ws + 3*RB);            // samp
    float* abuf  = (float*)(ws + 4*RB);            // attn-out / ffn-out
    u16* qkb = (u16*)(ws + 5*RB);                              // 7200x512 bf16
    u16* vb  = (u16*)(ws + 5*RB + (size_t)ROWS*QKS*2);         // 7200x256 bf16
    float* oab = (float*)(ws + 5*RB + (size_t)ROWS*QKS*2 + (size_t)ROWS*CDIM*2);   // 7200x480 f32
    char* wsm = ws + 5*RB + (size_t)ROWS*QKS*2 + (size_t)ROWS*CDIM*2 + (size_t)ROWS*OAS*4;
    u16* WqkT  = (u16*)(wsm);                       // 512x256
    u16* WvT   = (u16*)(wsm + 262144);
    u16* WoT   = (u16*)(wsm + 262144 + 1*131072);
    u16* WvalT = (u16*)(wsm + 262144 + 2*131072);
    u16* WoutT = (u16*)(wsm + 262144 + 3*131072);
    u16* WoaT  = (u16*)(wsm + 262144 + 4*131072);   // 480x256 (pad to 512 rows)
    u16* W1T   = (u16*)(wsm + 2*262144 + 4*131072);             // 2048x256
    u16* W2T   = (u16*)(wsm + 2*262144 + 4*131072 + 1048576);   // 256x2048
    float* bqk = (float*)(wsm + 2*262144 + 4*131072 + 2097152);
    float* boa = (float*)(wsm + 2*262144 + 4*131072 + 2097152 + 2048);
    char* big  = wsm + 2*262144 + 4*131072 + 2097152 + 4096;
    u16* valb  = (u16*)big;                         // 174592x256 bf16 (89.4MB)
    u16* ffnh  = (u16*)(big + (size_t)VROWS*CDIM*2);// 7200x2048 bf16

    const dim3 blk(256);

    // ---- prep: all weight transposes (scale folded into Wq/bq) + bias concat ----
    PrepArgs pa = { Wq, Wk, Wv, Wo, Wval, Wout, Woff, Watt, W1, W2,
                    WqkT, WvT, WoT, WvalT, WoutT, WoaT, W1T, W2T,
                    bq, bk, boff, batt, bqk, boa };
    prep_kernel<<<dim3(1529), blk, 0, stream>>>(pa);

    // ---- merged value | qk | v GEMMs ----
    mgemm3_kernel<<<dim3(3070), blk, 32768, stream>>>(
        memory, WvalT, bval, valb,
        tgt, qpos, WqkT, bqk, qkb,
        tgt, WvT, bv, vb);

    // ---- stage 1: self-attention ----
    attn_mfma_kernel<<<dim3(512), blk, 0, stream>>>(qkb, vb, abuf);
    gemm_direct<float,0,0,float><<<dim3(2,57), blk, 0, stream>>>(abuf, nullptr, WoT, bo, qk, ROWS, CDIM, CDIM);
    ln_res_kernel<<<dim3(ROWS/4), blk, 0, stream>>>(qk, tgt, ln2g, ln2b, tgt2);

    // ---- stage 2: deformable cross-attention ----
    gemm_direct<float,0,1,float><<<dim3(4,57), blk, 0, stream>>>(tgt2, qpos, WoaT, boa, oab, ROWS, OAS, CDIM);
    softmax20_kernel<<<dim3((ROWS*NH+255)/256), blk, 0, stream>>>(oab);
    msdeform_kernel<<<dim3(ROWS*NH/32), blk, 0, stream>>>(valb, oab, refpts, vbuf);
    gemm_direct<float,0,0,float><<<dim3(2,57), blk, 0, stream>>>(vbuf, nullptr, WoutT, bout, qk, ROWS, CDIM, CDIM);
    ln_res_kernel<<<dim3(ROWS/4), blk, 0, stream>>>(qk, tgt2, ln1g, ln1b, tgt3);

    // ---- stage 3: FFN ----
    gemm_direct<float,1,0,u16><<<dim3(16,57), blk, 32768, stream>>>(tgt3, nullptr, W1T, b1, ffnh, ROWS, DFF, CDIM);
    gemm_direct<u16,0,0,float><<<dim3(2,57),  blk, 0, stream>>>(ffnh, nullptr, W2T, b2, abuf, ROWS, CDIM, DFF);
    ln_res_kernel<<<dim3(ROWS/4), blk, 0, stream>>>(abuf, tgt3, ln3g, ln3b, out);
}

// Round 11
// 323.616 us; speedup vs baseline: 1.5078x; 1.5078x over previous
//
#include <hip/hip_runtime.h>
#include <hip/hip_bf16.h>
#include <type_traits>

#define LQ    900
#define BSZ   8
#define ROWS  (LQ*BSZ)        // 7200
#define CDIM  256
#define QKS   512             // merged q|k row stride
#define OAS   480             // merged off|aw row stride
#define NH    8
#define DH    32
#define LVTOT 21824
#define VROWS (LVTOT*BSZ)     // 174592
#define DFF   2048

typedef unsigned short u16;
typedef short short8 __attribute__((ext_vector_type(8)));
typedef float f32x4 __attribute__((ext_vector_type(4)));

__device__ __forceinline__ u16 f2bf(float f) {
    __hip_bfloat16 h = __float2bfloat16(f);
    return *reinterpret_cast<u16*>(&h);
}
#define ATTN_SCALE 0.1767766952966369f
// row-dependent chunk swizzle for BK=32 tiles (4 chunks of 16B per row)
#define SWZ(r) (((r) & 3) ^ (((r) >> 2) & 3))

// ---------------- unified prep: 10 weight transposes (+scale) + bias concat ----------------
struct PrepArgs {
    const float* Wq; const float* Wk; const float* Wv; const float* Wo;
    const float* Wval; const float* Wout; const float* Woff; const float* Watt;
    const float* W1; const float* W2;
    u16* WqkT; u16* WvT; u16* WoT; u16* WvalT; u16* WoutT; u16* WoaT; u16* W1T; u16* W2T;
    const float* bq; const float* bk; const float* boff; const float* batt;
    float* bqk; float* boa;
};
__global__ __launch_bounds__(256) void prep_kernel(PrepArgs a) {
    __shared__ float t[32][33];
    const int id = blockIdx.x;
    if (id == 1528) {   // bias concat (scale folded into bq)
        const int tx = threadIdx.x;
        if (tx < 256) { a.bqk[tx] = a.bq[tx] * ATTN_SCALE; a.bqk[256 + tx] = a.bk[tx]; }
        for (int i = tx; i < 320; i += 256) a.boa[i] = a.boff[i];
        if (tx < 160) a.boa[320 + tx] = a.batt[tx];
        return;
    }
    const float* W; u16* Wt; int K = 256, N = 256, nx = 8; float scale = 1.f; int r;
    if      (id < 64)   { W = a.Wq;   Wt = a.WqkT;           scale = ATTN_SCALE; r = id; }
    else if (id < 128)  { W = a.Wk;   Wt = a.WqkT + 256*256; r = id - 64; }
    else if (id < 192)  { W = a.Wv;   Wt = a.WvT;            r = id - 128; }
    else if (id < 256)  { W = a.Wo;   Wt = a.WoT;            r = id - 192; }
    else if (id < 320)  { W = a.Wval; Wt = a.WvalT;          r = id - 256; }
    else if (id < 384)  { W = a.Wout; Wt = a.WoutT;          r = id - 320; }
    else if (id < 464)  { W = a.Woff; Wt = a.WoaT;           N = 320; nx = 10; r = id - 384; }
    else if (id < 504)  { W = a.Watt; Wt = a.WoaT + 320*256; N = 160; nx = 5;  r = id - 464; }
    else if (id < 1016) { W = a.W1;   Wt = a.W1T;            N = 2048; nx = 64; r = id - 504; }
    else                { W = a.W2;   Wt = a.W2T;            K = 2048; N = 256; nx = 8; r = id - 1016; }
    const int n0 = (r % nx) * 32, k0 = (r / nx) * 32;
    const int tx = threadIdx.x & 31, ty = threadIdx.x >> 5;
    #pragma unroll
    for (int rr = ty; rr < 32; rr += 8)
        t[rr][tx] = W[(size_t)(k0 + rr) * N + n0 + tx];
    __syncthreads();
    #pragma unroll
    for (int rr = ty; rr < 32; rr += 8)
        Wt[(size_t)(n0 + rr) * K + k0 + tx] = f2bf(t[tx][rr] * scale);
}

// ---------------- staging helpers (BK=32, 512 threads) ----------------
// one 16B gload_lds per thread: linear LDS dest, inverse-swizzled global source
__device__ __forceinline__ void stage512(const u16* __restrict__ src, u16* dst,
                                         int row0, int K, int k0, int maxrow, int tid) {
    const int sr = tid >> 2, sc = tid & 3;
    int grow = row0 + sr; if (grow > maxrow) grow = maxrow;
    const u16* gsrc = src + (size_t)grow * K + k0 + ((sc ^ SWZ(sr)) << 3);
    u16* ldst = dst + ((tid & ~63) << 3);
    __builtin_amdgcn_global_load_lds((const __attribute__((address_space(1))) void*)gsrc,
                                     (__attribute__((address_space(3))) void*)ldst, 16, 0, 0);
}

template<int ADD>
__device__ __forceinline__ void load_A8(float* f, const float* __restrict__ A,
                                        const float* __restrict__ A2,
                                        int arow, int K, int k0, int sc) {
    const float4* src = reinterpret_cast<const float4*>(&A[(size_t)arow * K + k0 + sc * 8]);
    float4 v0 = src[0], v1 = src[1];
    if (ADD) {
        const float4* s2 = reinterpret_cast<const float4*>(&A2[(size_t)arow * K + k0 + sc * 8]);
        float4 g0 = s2[0], g1 = s2[1];
        v0.x += g0.x; v0.y += g0.y; v0.z += g0.z; v0.w += g0.w;
        v1.x += g1.x; v1.y += g1.y; v1.z += g1.z; v1.w += g1.w;
    }
    f[0]=v0.x; f[1]=v0.y; f[2]=v0.z; f[3]=v0.w;
    f[4]=v1.x; f[5]=v1.y; f[6]=v1.z; f[7]=v1.w;
}

__device__ __forceinline__ void write_A8(u16* Adst, const float* f, int sr, int sc) {
    u16 t[8];
    #pragma unroll
    for (int i = 0; i < 8; ++i) t[i] = f2bf(f[i]);
    *reinterpret_cast<uint4*>(&Adst[sr*32 + ((sc ^ SWZ(sr)) * 8)]) =
        *reinterpret_cast<const uint4*>(t);
}

// ---------------- bf16 MFMA GEMM body: 512 threads, 8 waves (2x4), 64x32/wave ----------------
// acc = 4x2 f32x4 = 32 AGPR -> ~92 total regs -> 2 blocks/CU (16 waves) occupancy.
template<typename AT, int RELU, int ADD, typename OutT>
__device__ __forceinline__ void gemm_body(const AT* __restrict__ A, const float* __restrict__ A2,
                                          const u16* __restrict__ Wt, const float* __restrict__ bias,
                                          OutT* __restrict__ C, int M, int N, int K,
                                          int m0, int n0, int tid, u16* S) {
    const int lane = tid & 63;
    const int w = tid >> 6;
    const int wr = w >> 2, wc = w & 3;         // 2 x 4 wave grid
    const int lr = lane & 15, lg = lane >> 4;
    const int sr = tid >> 2, sc = tid & 3;
    const int ns = K >> 5;
    const int arow = (m0 + sr < M) ? (m0 + sr) : (M - 1);

    f32x4 acc[4][2] = {};
    float fa[8];

    // prologue: tile 0
    stage512(Wt, S + 8192, n0, K, 0, N - 1, tid);
    if constexpr (std::is_same<AT, float>::value) {
        load_A8<ADD>(fa, A, A2, arow, K, 0, sc);
        write_A8(S, fa, sr, sc);
    } else {
        stage512((const u16*)A, S, m0, K, 0, M - 1, tid);
    }
    __syncthreads();

    for (int t = 0; t < ns; ++t) {
        u16* Ac = S + ((t & 1) << 12);
        u16* Bc = S + 8192 + ((t & 1) << 12);
        const int nxt = (t + 1) & 1;
        if (t + 1 < ns) {
            stage512(Wt, S + 8192 + (nxt << 12), n0, K, (t + 1) << 5, N - 1, tid);
            if constexpr (std::is_same<AT, float>::value)
                load_A8<ADD>(fa, A, A2, arow, K, (t + 1) << 5, sc);
            else
                stage512((const u16*)A, S + (nxt << 12), m0, K, (t + 1) << 5, M - 1, tid);
        }
        short8 af[4], bf[2];
        #pragma unroll
        for (int i = 0; i < 4; ++i) {
            const int r = wr*64 + i*16 + lr;
            af[i] = *reinterpret_cast<const short8*>(&Ac[r*32 + ((lg ^ SWZ(r)) * 8)]);
        }
        #pragma unroll
        for (int j = 0; j < 2; ++j) {
            const int rb = wc*32 + j*16 + lr;
            bf[j] = *reinterpret_cast<const short8*>(&Bc[rb*32 + ((lg ^ SWZ(rb)) * 8)]);
        }
        #pragma unroll
        for (int i = 0; i < 4; ++i)
            #pragma unroll
            for (int j = 0; j < 2; ++j)
                acc[i][j] = __builtin_amdgcn_mfma_f32_16x16x32_bf16(af[i], bf[j], acc[i][j], 0, 0, 0);
        if (t + 1 < ns) {
            if constexpr (std::is_same<AT, float>::value)
                write_A8(S + (nxt << 12), fa, sr, sc);
        }
        __syncthreads();
    }

    if constexpr (std::is_same<OutT, float>::value) {
        #pragma unroll
        for (int j = 0; j < 2; ++j) {
            const int col = n0 + wc*32 + j*16 + lr;
            if (col >= N) continue;
            const float bcol = bias[col];
            #pragma unroll
            for (int i = 0; i < 4; ++i) {
                #pragma unroll
                for (int r = 0; r < 4; ++r) {
                    const int row = m0 + wr*64 + i*16 + lg*4 + r;
                    if (row >= M) continue;
                    float v = acc[i][j][r] + bcol;
                    if (RELU) v = fmaxf(v, 0.f);
                    C[(size_t)row * N + col] = v;
                }
            }
        }
    } else {
        // LDS-staged coalesced bf16 epilogue (N multiple of 128 on this path)
        __syncthreads();
        u16* Ct = S;   // full 32KB = 128x128 bf16
        #pragma unroll
        for (int j = 0; j < 2; ++j) {
            const int col = wc*32 + j*16 + lr;
            const float bcol = bias[n0 + col];
            #pragma unroll
            for (int i = 0; i < 4; ++i)
                #pragma unroll
                for (int r = 0; r < 4; ++r) {
                    float v = acc[i][j][r] + bcol;
                    if (RELU) v = fmaxf(v, 0.f);
                    Ct[(wr*64 + i*16 + lg*4 + r)*128 + col] = f2bf(v);
                }
        }
        __syncthreads();
        #pragma unroll
        for (int it = 0; it < 4; ++it) {
            const int idx = it*512 + tid;
            const int row = idx >> 4, cc = idx & 15;
            if (m0 + row < M)
                *reinterpret_cast<uint4*>(&C[(size_t)(m0 + row) * N + n0 + cc*8]) =
                    *reinterpret_cast<const uint4*>(&Ct[row*128 + cc*8]);
        }
    }
}

template<typename AT, int RELU, int ADD, typename OutT>
__global__ __launch_bounds__(512) void gemm_mfma(const AT* __restrict__ A, const float* __restrict__ A2,
                                                 const u16* __restrict__ Wt, const float* __restrict__ bias,
                                                 OutT* __restrict__ C, int M, int N, int K) {
    __shared__ __align__(16) u16 S[16384];
    gemm_body<AT, RELU, ADD, OutT>(A, A2, Wt, bias, C, M, N, K,
                                   blockIdx.y * 128, blockIdx.x * 128, threadIdx.x, S);
}

// merged value | qk | v dispatch (all K=256, bf16 out)
__global__ __launch_bounds__(512) void mgemm3_kernel(
        const float* __restrict__ Aval, const u16* __restrict__ WvalT, const float* __restrict__ bval, u16* __restrict__ Cval,
        const float* __restrict__ Aqk,  const float* __restrict__ Aqk2, const u16* __restrict__ WqkT,
        const float* __restrict__ bqk,  u16* __restrict__ Cqk,
        const float* __restrict__ Av,   const u16* __restrict__ WvT,   const float* __restrict__ bv, u16* __restrict__ Cv) {
    __shared__ __align__(16) u16 S[16384];
    int id = blockIdx.x;
    if (id < 2728) {
        gemm_body<float,0,0,u16>(Aval, nullptr, WvalT, bval, Cval, VROWS, 256, 256,
                                 (id >> 1) * 128, (id & 1) * 128, threadIdx.x, S);
    } else if (id < 2956) {
        id -= 2728;
        gemm_body<float,0,1,u16>(Aqk, Aqk2, WqkT, bqk, Cqk, ROWS, 512, 256,
                                 (id >> 2) * 128, (id & 3) * 128, threadIdx.x, S);
    } else {
        id -= 2956;
        gemm_body<float,0,0,u16>(Av, nullptr, WvT, bv, Cv, ROWS, 256, 256,
                                 (id >> 1) * 128, (id & 1) * 128, threadIdx.x, S);
    }
}

// ---------------- MFMA flash self-attention (bf16 q/k/v in) ----------------
__global__ __launch_bounds__(256) void attn_mfma_kernel(const u16* __restrict__ qkb,
                                                        const u16* __restrict__ vb,
                                                        float* __restrict__ out) {
    __shared__ __align__(16) u16 Ks[64*32];
    __shared__ __align__(16) u16 Vt[32*64];
    const int bx = blockIdx.x;
    const int qt = bx & 7, h = (bx >> 3) & 7, b = bx >> 6;
    const int tid = threadIdx.x;
    const int w = tid >> 6, lane = tid & 63;
    const int lr = lane & 15, lg = lane >> 4;
    const int m0 = qt*128 + w*32;

    short8 qf[2];
    #pragma unroll
    for (int j = 0; j < 2; ++j) {
        int lq = m0 + j*16 + lr; if (lq > LQ-1) lq = LQ-1;
        qf[j] = *reinterpret_cast<const short8*>(&qkb[((size_t)lq*BSZ + b)*QKS + h*DH + lg*8]);
    }

    f32x4 o00 = {}, o01 = {}, o10 = {}, o11 = {};
    float m[2] = {-1e30f, -1e30f}, l[2] = {0.f, 0.f};
    const f32x4 zero = {};

    for (int kt = 0; kt < 15; ++kt) {
        __syncthreads();
        {
            const int key = tid >> 2, c = tid & 3;
            int kg = kt*64 + key; if (kg > LQ-1) kg = LQ-1;
            *reinterpret_cast<short8*>(&Ks[key*32 + ((c ^ ((key>>1)&3)) * 8)]) =
                *reinterpret_cast<const short8*>(&qkb[((size_t)kg*BSZ + b)*QKS + 256 + h*DH + c*8]);
            short8 vv = *reinterpret_cast<const short8*>(&vb[((size_t)kg*BSZ + b)*CDIM + h*DH + c*8]);
            const u16* pv = reinterpret_cast<const u16*>(&vv);
            #pragma unroll
            for (int e = 0; e < 8; ++e) {
                const int dh = c*8 + e;
                Vt[dh*64 + (((key>>3) ^ (dh&7)) * 8) + (key&7)] = pv[e];
            }
        }
        __syncthreads();

        f32x4 s[4][2];
        #pragma unroll
        for (int i = 0; i < 4; ++i) {
            const int key = i*16 + lr;
            short8 kf = *reinterpret_cast<const short8*>(&Ks[key*32 + ((lg ^ ((key>>1)&3)) * 8)]);
            s[i][0] = __builtin_amdgcn_mfma_f32_16x16x32_bf16(kf, qf[0], zero, 0, 0, 0);
            s[i][1] = __builtin_amdgcn_mfma_f32_16x16x32_bf16(kf, qf[1], zero, 0, 0, 0);
        }
        const int lim = LQ - kt*64 - lg*4;
        #pragma unroll
        for (int i = 0; i < 4; ++i)
            #pragma unroll
            for (int r = 0; r < 4; ++r)
                if (i*16 + r >= lim) { s[i][0][r] = -1e30f; s[i][1][r] = -1e30f; }

        #pragma unroll
        for (int j = 0; j < 2; ++j) {
            float mx = -1e30f;
            #pragma unroll
            for (int i = 0; i < 4; ++i)
                #pragma unroll
                for (int r = 0; r < 4; ++r) mx = fmaxf(mx, s[i][j][r]);
            mx = fmaxf(mx, __shfl_xor(mx, 16));
            mx = fmaxf(mx, __shfl_xor(mx, 32));
            const float mn = fmaxf(m[j], mx);
            const float corr = __expf(m[j] - mn);
            float sum = 0.f;
            #pragma unroll
            for (int i = 0; i < 4; ++i)
                #pragma unroll
                for (int r = 0; r < 4; ++r) {
                    float p = __expf(s[i][j][r] - mn);
                    s[i][j][r] = p;
                    sum += p;
                }
            sum += __shfl_xor(sum, 16);
            sum += __shfl_xor(sum, 32);
            l[j] = l[j]*corr + sum;
            m[j] = mn;
            if (j == 0) { o00 *= corr; o10 *= corr; }
            else        { o01 *= corr; o11 *= corr; }
        }

        short8 pb[2][2];
        #pragma unroll
        for (int kh = 0; kh < 2; ++kh)
            #pragma unroll
            for (int j = 0; j < 2; ++j) {
                u16 t[8];
                #pragma unroll
                for (int e = 0; e < 4; ++e) {
                    t[e]   = f2bf(s[2*kh][j][e]);
                    t[e+4] = f2bf(s[2*kh+1][j][e]);
                }
                pb[kh][j] = *reinterpret_cast<short8*>(t);
            }

        #pragma unroll
        for (int ip = 0; ip < 2; ++ip) {
            const int dh = ip*16 + lr;
            #pragma unroll
            for (int kh = 0; kh < 2; ++kh) {
                u16 t[8];
                const int c0 = (kh*4 + (lg>>1)) ^ (dh&7);
                const int c1 = (kh*4 + 2 + (lg>>1)) ^ (dh&7);
                *reinterpret_cast<uint2*>(&t[0]) =
                    *reinterpret_cast<const uint2*>(&Vt[dh*64 + c0*8 + (lg&1)*4]);
                *reinterpret_cast<uint2*>(&t[4]) =
                    *reinterpret_cast<const uint2*>(&Vt[dh*64 + c1*8 + (lg&1)*4]);
                short8 vf = *reinterpret_cast<short8*>(t);
                if (ip == 0) {
                    o00 = __builtin_amdgcn_mfma_f32_16x16x32_bf16(vf, pb[kh][0], o00, 0, 0, 0);
                    o01 = __builtin_amdgcn_mfma_f32_16x16x32_bf16(vf, pb[kh][1], o01, 0, 0, 0);
                } else {
                    o10 = __builtin_amdgcn_mfma_f32_16x16x32_bf16(vf, pb[kh][0], o10, 0, 0, 0);
                    o11 = __builtin_amdgcn_mfma_f32_16x16x32_bf16(vf, pb[kh][1], o11, 0, 0, 0);
                }
            }
        }
    }

    #pragma unroll
    for (int j = 0; j < 2; ++j) {
        const int lq = m0 + j*16 + lr;
        if (lq >= LQ) continue;
        const float inv = 1.f / l[j];
        float* op = &out[((size_t)lq*BSZ + b)*CDIM + h*DH];
        #pragma unroll
        for (int r = 0; r < 4; ++r) {
            const f32x4& a0 = (j == 0) ? o00 : o01;
            const f32x4& a1 = (j == 0) ? o10 : o11;
            op[lg*4 + r]      = a0[r] * inv;
            op[16 + lg*4 + r] = a1[r] * inv;
        }
    }
}

// ---------------- fused residual + LayerNorm ----------------
__global__ __launch_bounds__(256) void ln_res_kernel(const float* __restrict__ xin,
                                                     const float* __restrict__ res,
                                                     const float* __restrict__ g,
                                                     const float* __restrict__ beta,
                                                     float* __restrict__ out) {
    const int row  = blockIdx.x * 4 + (threadIdx.x >> 6);
    const int lane = threadIdx.x & 63;
    const size_t base = (size_t)row * CDIM + lane * 4;
    float4 a = *reinterpret_cast<const float4*>(&xin[base]);
    float4 r = *reinterpret_cast<const float4*>(&res[base]);
    float x0 = a.x+r.x, x1 = a.y+r.y, x2 = a.z+r.z, x3 = a.w+r.w;
    float s = x0+x1+x2+x3;
    #pragma unroll
    for (int o = 1; o < 64; o <<= 1) s += __shfl_xor(s, o);
    float mean = s * (1.f/256.f);
    float d0 = x0-mean, d1 = x1-mean, d2 = x2-mean, d3 = x3-mean;
    float sq = d0*d0 + d1*d1 + d2*d2 + d3*d3;
    #pragma unroll
    for (int o = 1; o < 64; o <<= 1) sq += __shfl_xor(sq, o);
    float rs = rsqrtf(sq * (1.f/256.f) + 1e-5f);
    float4 gg = *reinterpret_cast<const float4*>(&g[lane*4]);
    float4 bb = *reinterpret_cast<const float4*>(&beta[lane*4]);
    float4 o4 = make_float4(d0*rs*gg.x+bb.x, d1*rs*gg.y+bb.y, d2*rs*gg.z+bb.z, d3*rs*gg.w+bb.w);
    *reinterpret_cast<float4*>(&out[base]) = o4;
}

// ---------------- softmax over 20 (in merged oab buffer, offset 320) ----------------
__global__ __launch_bounds__(256) void softmax20_kernel(float* __restrict__ oab) {
    int item = blockIdx.x * 256 + threadIdx.x;
    if (item >= ROWS * NH) return;
    int row = item >> 3, h = item & 7;
    float* p = &oab[(size_t)row*OAS + 320 + h*20];
    float mx = -1e30f;
    float e[20];
    #pragma unroll
    for (int j = 0; j < 20; ++j) mx = fmaxf(mx, p[j]);
    float sum = 0.f;
    #pragma unroll
    for (int j = 0; j < 20; ++j) { e[j] = __expf(p[j] - mx); sum += e[j]; }
    float inv = 1.f / sum;
    #pragma unroll
    for (int j = 0; j < 20; ++j) p[j] = e[j] * inv;
}

// ---------------- ms-deformable sampling ----------------
__global__ __launch_bounds__(256) void msdeform_kernel(const u16* __restrict__ value,
                                                       const float* __restrict__ oab,
                                                       const float* __restrict__ refp,
                                                       float* __restrict__ samp) {
    const int gid = blockIdx.x * 32 + (threadIdx.x >> 3);  // row*8 + h
    const int ch  = (threadIdx.x & 7) * 4;
    const int h   = gid & 7;
    const int row = gid >> 3;
    const int b   = row & 7;
    const int WL[5] = {128, 64, 32, 16, 8};
    const int SL[5] = {0, 16384, 20480, 21504, 21760};
    const u16* vbase = value + h*DH + ch;
    float a0 = 0.f, a1 = 0.f, a2 = 0.f, a3 = 0.f;
    #pragma unroll
    for (int l = 0; l < 5; ++l) {
        const float2 r2 = *reinterpret_cast<const float2*>(&refp[((size_t)row*5 + l)*2]);
        const int W = WL[l];
        const float Wf = (float)W;
        #pragma unroll
        for (int p = 0; p < 4; ++p) {
            const float2 o2 = *reinterpret_cast<const float2*>(&oab[(size_t)row*OAS + ((h*5 + l)*4 + p)*2]);
            const float aw = oab[(size_t)row*OAS + 320 + h*20 + l*4 + p];
            const float x = (r2.x + o2.x / Wf) * Wf - 0.5f;
            const float y = (r2.y + o2.y / Wf) * Wf - 0.5f;
            const float x0f = floorf(x), y0f = floorf(y);
            const float fx = x - x0f, fy = y - y0f;
            const int x0 = (int)x0f, y0 = (int)y0f;
            float wx0 = (1.f - fx) * aw, wx1 = fx * aw;
            float fy0 = 1.f - fy, fy1 = fy;
            if (x0 < 0 || x0 >= W)       wx0 = 0.f;
            if (x0+1 < 0 || x0+1 >= W)   wx1 = 0.f;
            if (y0 < 0 || y0 >= W)       fy0 = 0.f;
            if (y0+1 < 0 || y0+1 >= W)   fy1 = 0.f;
            const float w00 = wx0*fy0, w10 = wx1*fy0, w01 = wx0*fy1, w11 = wx1*fy1;
            const int xc0 = min(max(x0, 0), W-1),   xc1 = min(max(x0+1, 0), W-1);
            const int yc0 = min(max(y0, 0), W-1),   yc1 = min(max(y0+1, 0), W-1);
            const int r0 = SL[l] + yc0*W, r1 = SL[l] + yc1*W;
            const int o00i = ((r0 + xc0)*BSZ + b) * CDIM;
            const int o10i = ((r0 + xc1)*BSZ + b) * CDIM;
            const int o01i = ((r1 + xc0)*BSZ + b) * CDIM;
            const int o11i = ((r1 + xc1)*BSZ + b) * CDIM;
            const uint2 u00 = *reinterpret_cast<const uint2*>(vbase + o00i);
            const uint2 u10 = *reinterpret_cast<const uint2*>(vbase + o10i);
            const uint2 u01 = *reinterpret_cast<const uint2*>(vbase + o01i);
            const uint2 u11 = *reinterpret_cast<const uint2*>(vbase + o11i);
            a0 += w00 * __uint_as_float(u00.x << 16) + w10 * __uint_as_float(u10.x << 16)
                + w01 * __uint_as_float(u01.x << 16) + w11 * __uint_as_float(u11.x << 16);
            a1 += w00 * __uint_as_float(u00.x & 0xffff0000u) + w10 * __uint_as_float(u10.x & 0xffff0000u)
                + w01 * __uint_as_float(u01.x & 0xffff0000u) + w11 * __uint_as_float(u11.x & 0xffff0000u);
            a2 += w00 * __uint_as_float(u00.y << 16) + w10 * __uint_as_float(u10.y << 16)
                + w01 * __uint_as_float(u01.y << 16) + w11 * __uint_as_float(u11.y << 16);
            a3 += w00 * __uint_as_float(u00.y & 0xffff0000u) + w10 * __uint_as_float(u10.y & 0xffff0000u)
                + w01 * __uint_as_float(u01.y & 0xffff0000u) + w11 * __uint_as_float(u11.y & 0xffff0000u);
        }
    }
    float4 o4 = make_float4(a0, a1, a2, a3);
    *reinterpret_cast<float4*>(&samp[(size_t)row*CDIM + h*DH + ch]) = o4;
}

// ---------------- launch ----------------
extern "C" void kernel_launch(void* const* d_in, const int* in_sizes, int n_in,
                              void* d_out, int out_size, void* d_ws, size_t ws_size,
                              hipStream_t stream) {
    (void)in_sizes; (void)n_in; (void)out_size; (void)ws_size;
    const float* tgt    = (const float*)d_in[0];
    const float* qpos   = (const float*)d_in[1];
    const float* refpts = (const float*)d_in[2];
    const float* memory = (const float*)d_in[3];
    const float* Wq  = (const float*)d_in[6];
    const float* Wk  = (const float*)d_in[7];
    const float* Wv  = (const float*)d_in[8];
    const float* Wo  = (const float*)d_in[9];
    const float* Woff= (const float*)d_in[10];
    const float* Watt= (const float*)d_in[11];
    const float* Wval= (const float*)d_in[12];
    const float* Wout= (const float*)d_in[13];
    const float* W1  = (const float*)d_in[14];
    const float* W2  = (const float*)d_in[15];
    const float* bq  = (const float*)d_in[16];
    const float* bk  = (const float*)d_in[17];
    const float* bv  = (const float*)d_in[18];
    const float* bo  = (const float*)d_in[19];
    const float* boff= (const float*)d_in[20];
    const float* batt= (const float*)d_in[21];
    const float* bval= (const float*)d_in[22];
    const float* bout= (const float*)d_in[23];
    const float* b1  = (const float*)d_in[24];
    const float* b2  = (const float*)d_in[25];
    const float* ln1g= (const float*)d_in[26];
    const float* ln1b= (const float*)d_in[27];
    const float* ln2g= (const float*)d_in[28];
    const float* ln2b= (const float*)d_in[29];
    const float* ln3g= (const float*)d_in[30];
    const float* ln3b= (const float*)d_in[31];
    float* out = (float*)d_out;

    char* ws = (char*)d_ws;
    const size_t RB = (size_t)ROWS * CDIM * 4;     // 7.37 MB
    float* tgt2  = (float*)(ws + 0*RB);
    float* tgt3  = (float*)(ws + 1*RB);
    float* qk    = (float*)(ws + 2*RB);            // sa-o / ca-o
    float* vbuf  = (float*)(ws + 3*RB);            // samp
    float* abuf  = (float*)(ws + 4*RB);            // attn-out / ffn-out
    u16* qkb = (u16*)(ws + 5*RB);                              // 7200x512 bf16
    u16* vb  = (u16*)(ws + 5*RB + (size_t)ROWS*QKS*2);         // 7200x256 bf16
    float* oab = (float*)(ws + 5*RB + (size_t)ROWS*QKS*2 + (size_t)ROWS*CDIM*2);   // 7200x480 f32
    char* wsm = ws + 5*RB + (size_t)ROWS*QKS*2 + (size_t)ROWS*CDIM*2 + (size_t)ROWS*OAS*4;
    u16* WqkT  = (u16*)(wsm);                       // 512x256
    u16* WvT   = (u16*)(wsm + 262144);
    u16* WoT   = (u16*)(wsm + 262144 + 1*131072);
    u16* WvalT = (u16*)(wsm + 262144 + 2*131072);
    u16* WoutT = (u16*)(wsm + 262144 + 3*131072);
    u16* WoaT  = (u16*)(wsm + 262144 + 4*131072);   // 480x256 (pad to 512 rows)
    u16* W1T   = (u16*)(wsm + 2*262144 + 4*131072);             // 2048x256
    u16* W2T   = (u16*)(wsm + 2*262144 + 4*131072 + 1048576);   // 256x2048
    float* bqk = (float*)(wsm + 2*262144 + 4*131072 + 2097152);
    float* boa = (float*)(wsm + 2*262144 + 4*131072 + 2097152 + 2048);
    char* big  = wsm + 2*262144 + 4*131072 + 2097152 + 4096;
    u16* valb  = (u16*)big;                         // 174592x256 bf16 (89.4MB)
    u16* ffnh  = (u16*)(big + (size_t)VROWS*CDIM*2);// 7200x2048 bf16

    const dim3 blk(256);
    const dim3 blk512(512);

    // ---- prep: all weight transposes (scale folded into Wq/bq) + bias concat ----
    PrepArgs pa = { Wq, Wk, Wv, Wo, Wval, Wout, Woff, Watt, W1, W2,
                    WqkT, WvT, WoT, WvalT, WoutT, WoaT, W1T, W2T,
                    bq, bk, boff, batt, bqk, boa };
    prep_kernel<<<dim3(1529), blk, 0, stream>>>(pa);

    // ---- merged value | qk | v GEMMs ----
    mgemm3_kernel<<<dim3(3070), blk512, 0, stream>>>(
        memory, WvalT, bval, valb,
        tgt, qpos, WqkT, bqk, qkb,
        tgt, WvT, bv, vb);

    // ---- stage 1: self-attention ----
    attn_mfma_kernel<<<dim3(512), blk, 0, stream>>>(qkb, vb, abuf);
    gemm_mfma<float,0,0,float><<<dim3(2,57), blk512, 0, stream>>>(abuf, nullptr, WoT, bo, qk, ROWS, CDIM, CDIM);
    ln_res_kernel<<<dim3(ROWS/4), blk, 0, stream>>>(qk, tgt, ln2g, ln2b, tgt2);

    // ---- stage 2: deformable cross-attention ----
    gemm_mfma<float,0,1,float><<<dim3(4,57), blk512, 0, stream>>>(tgt2, qpos, WoaT, boa, oab, ROWS, OAS, CDIM);
    softmax20_kernel<<<dim3((ROWS*NH+255)/256), blk, 0, stream>>>(oab);
    msdeform_kernel<<<dim3(ROWS*NH/32), blk, 0, stream>>>(valb, oab, refpts, vbuf);
    gemm_mfma<float,0,0,float><<<dim3(2,57), blk512, 0, stream>>>(vbuf, nullptr, WoutT, bout, qk, ROWS, CDIM, CDIM);
    ln_res_kernel<<<dim3(ROWS/4), blk, 0, stream>>>(qk, tgt2, ln1g, ln1b, tgt3);

    // ---- stage 3: FFN ----
    gemm_mfma<float,1,0,u16><<<dim3(16,57), blk512, 0, stream>>>(tgt3, nullptr, W1T, b1, ffnh, ROWS, DFF, CDIM);
    gemm_mfma<u16,0,0,float><<<dim3(2,57),  blk512, 0, stream>>>(ffnh, nullptr, W2T, b2, abuf, ROWS, CDIM, DFF);
    ln_res_kernel<<<dim3(ROWS/4), blk, 0, stream>>>(abuf, tgt3, ln3g, ln3b, out);
}